// Round 1
// 1013.053 us; speedup vs baseline: 1.0358x; 1.0358x over previous
//
#include <hip/hip_runtime.h>

// Sinkhorn-Knopp, factored: s_ij = a_ij * u_i * v_j; only u,v evolve.
// R3: counters showed dur 770us, VALUBusy 2.9%, HBM 790GB/s avg (10% peak),
// FETCH 223MB vs ~76MB demand, WRITE 382MB vs 268MB demand, VGPR_Count=128
// vs ~230 u32 live. Diagnosis: transaction/latency-bound global I/O (every
// load/store was 64-lane row-divergent: 64 cache lines per instr, 16B/lane)
// plus probable scratch spill at the 128-VGPR allocation.
// Fixes this round:
//  (1) waves_per_eu(2,2): force the 256-VGPR budget (1 block/CU anyway).
//  (2) All global I/O wave-coalesced (lane -> consecutive float4), staged
//      through LDS with an XOR quad swizzle (bank-balanced: 8 lanes/quad).
//  (3) Spill re-laid-out as 4 contiguous [32][256]-u32 chunks (k=12..15):
//      loader scatters bf16 pairs straight into place; chunk-12 region is
//      the 32KB load-staging buffer for register rows (load order 15,14,13,
//      then 0..11 staged, then 12); chunks 12+13 become the 64KB f32
//      store-staging buffer after the k>=12 outputs are flushed via red[].
#define SEPS 1e-10f

typedef unsigned int uu;
typedef uu v16u __attribute__((ext_vector_type(16)));

#define RPTK12(F) F(0) F(1) F(2) F(3) F(4) F(5) F(6) F(7) F(8) F(9) F(10) F(11)

__device__ __forceinline__ uu bfpack2(float f0, float f1) {
    uu u0 = __float_as_uint(f0 + SEPS);
    uu u1 = __float_as_uint(f1 + SEPS);
    u0 += 0x7FFFu + ((u0 >> 16) & 1u);   // RNE to bf16
    u1 += 0x7FFFu + ((u1 >> 16) & 1u);
    return (u0 >> 16) | (u1 & 0xFFFF0000u);  // low16 = even col, high16 = odd col
}

__global__
__attribute__((amdgpu_flat_work_group_size(512, 512)))
__attribute__((amdgpu_waves_per_eu(2, 2)))
void sinkhorn_kernel(const float* __restrict__ s, const int* __restrict__ nrows,
                     const int* __restrict__ ncols, float* __restrict__ out)
{
    // 4 chunks of [32 rows][256 u32] bf16-pairs, quad(16B)-swizzled: 128 KB
    __shared__ __align__(16) uu    spill[4 * 8192];
    __shared__ __align__(16) float red[8][516];   // iter partials; reused as 16KB store staging
    __shared__ float sh_u[512];
    __shared__ float sh_v[512];

    const int b   = blockIdx.x;
    const int tid = threadIdx.x;
    const int tr  = tid & 31;
    const int tc  = tid >> 5;
    const int c0  = tc << 5;
    const int wv  = tid >> 6;
    const int nr  = nrows[b];
    const int nc  = ncols[b];
    const bool cact = (c0 < nc);

    sh_u[tid] = 1.0f;

#define DECLR(k) v16u R##k;
    RPTK12(DECLR)

    const float4* sb4 = (const float4*)(s   + ((size_t)b << 18));
    float4*       ob4 = (float4*)      (out + ((size_t)b << 18));

    // ---- coalesced chunk stage: rows 32k..32k+31 -> dst [32][256] u32, swizzled.
    // f = float4 index in chunk; consecutive lanes -> consecutive 16B (coalesced).
    // Masks (row>=nr, col>=nc -> 0) applied here, so readers are pure copies.
#define STAGE_CHUNK(k, dst) { \
    _Pragma("unroll") \
    for (int i__ = 0; i__ < 8; ++i__) { \
        const int f__  = i__ * 512 + tid; \
        const int rr__ = f__ >> 7; \
        const int p__  = f__ & 127; \
        const int cc__ = p__ << 2; \
        const int r__  = 32*(k) + rr__; \
        float4 w__ = make_float4(0.f, 0.f, 0.f, 0.f); \
        if (r__ < nr && cc__ < nc) w__ = sb4[(k)*4096 + f__]; \
        const int rem__ = nc - cc__; \
        const uu mA__ = (rem__ >= 2) ? 0xFFFFFFFFu : ((rem__ == 1) ? 0x0000FFFFu : 0u); \
        const uu mB__ = (rem__ >= 4) ? 0xFFFFFFFFu : ((rem__ == 3) ? 0x0000FFFFu : 0u); \
        const uu rm__ = (r__ < nr) ? 0xFFFFFFFFu : 0u; \
        uint2 pr__; \
        pr__.x = bfpack2(w__.x, w__.y) & mA__ & rm__; \
        pr__.y = bfpack2(w__.z, w__.w) & mB__ & rm__; \
        *(uint2*)((dst) + rr__*256 + ((((p__ >> 1) ^ (rr__ & 7)) << 2) | ((p__ & 1) << 1))) = pr__; \
    } }

    // ---- distribute staged chunk (at spill[0]) into this thread's R##k
#define DIST_CHUNK(k) { \
    const uu* rb__ = spill + tr*256; \
    const int x__  = tr & 7; \
    uint4 t0__ = *(const uint4*)(rb__ + ((((tc<<2)+0) ^ x__) << 2)); \
    uint4 t1__ = *(const uint4*)(rb__ + ((((tc<<2)+1) ^ x__) << 2)); \
    uint4 t2__ = *(const uint4*)(rb__ + ((((tc<<2)+2) ^ x__) << 2)); \
    uint4 t3__ = *(const uint4*)(rb__ + ((((tc<<2)+3) ^ x__) << 2)); \
    R##k[0]=t0__.x;  R##k[1]=t0__.y;  R##k[2]=t0__.z;  R##k[3]=t0__.w; \
    R##k[4]=t1__.x;  R##k[5]=t1__.y;  R##k[6]=t1__.z;  R##k[7]=t1__.w; \
    R##k[8]=t2__.x;  R##k[9]=t2__.y;  R##k[10]=t2__.z; R##k[11]=t2__.w; \
    R##k[12]=t3__.x; R##k[13]=t3__.y; R##k[14]=t3__.z; R##k[15]=t3__.w; }

    // load order: 15,14,13 direct-scatter; 0..11 staged in chunk-12 region; 12 last
    if (480 < nr) STAGE_CHUNK(15, spill + 3*8192)
    if (448 < nr) STAGE_CHUNK(14, spill + 2*8192)
    if (416 < nr) STAGE_CHUNK(13, spill + 1*8192)
#define LOADK(k) if (32*(k) < nr) { \
    STAGE_CHUNK(k, spill) \
    __syncthreads(); \
    DIST_CHUNK(k) \
    __syncthreads(); }
    RPTK12(LOADK)
    if (384 < nr) STAGE_CHUNK(12, spill)
    __syncthreads();   // spill + sh_u visible

    // quad q of thread (tr,tc) in spill chunk k (k=12..15)
#define SPQ(k, q) ((const uint4*)(spill + ((k)-12)*8192 + tr*256 + ((((tc<<2)+(q)) ^ (tr & 7)) << 2)))

#define UFW(w, uk, A, B) { const uu w__ = (w); \
    A += __uint_as_float(w__ << 16) * (uk); \
    B += __uint_as_float(w__ & 0xFFFF0000u) * (uk); }

#define COLBODY(P, uk) \
    UFW(P[0],  uk, ca0,  ca1)  UFW(P[1],  uk, ca2,  ca3) \
    UFW(P[2],  uk, ca4,  ca5)  UFW(P[3],  uk, ca6,  ca7) \
    UFW(P[4],  uk, ca8,  ca9)  UFW(P[5],  uk, ca10, ca11) \
    UFW(P[6],  uk, ca12, ca13) UFW(P[7],  uk, ca14, ca15) \
    UFW(P[8],  uk, ca16, ca17) UFW(P[9],  uk, ca18, ca19) \
    UFW(P[10], uk, ca20, ca21) UFW(P[11], uk, ca22, ca23) \
    UFW(P[12], uk, ca24, ca25) UFW(P[13], uk, ca26, ca27) \
    UFW(P[14], uk, ca28, ca29) UFW(P[15], uk, ca30, ca31)

#define COLK(k) if (32*(k) < nr && cact) { \
    const float uk__ = sh_u[tr + 32*(k)]; \
    COLBODY(R##k, uk__) }

#define COLLDSQ(k, q, A0,A1,A2,A3,A4,A5,A6,A7) { \
    uint4 t__ = *SPQ(k,q); \
    UFW(t__.x, uk__, A0, A1) UFW(t__.y, uk__, A2, A3) \
    UFW(t__.z, uk__, A4, A5) UFW(t__.w, uk__, A6, A7) }

#define COLLDS(k) if (32*(k) < nr && cact) { \
    const float uk__ = sh_u[tr + 32*(k)]; \
    COLLDSQ(k,0, ca0,ca1,ca2,ca3,ca4,ca5,ca6,ca7) \
    COLLDSQ(k,1, ca8,ca9,ca10,ca11,ca12,ca13,ca14,ca15) \
    COLLDSQ(k,2, ca16,ca17,ca18,ca19,ca20,ca21,ca22,ca23) \
    COLLDSQ(k,3, ca24,ca25,ca26,ca27,ca28,ca29,ca30,ca31) }

#define TST(m, OUT, A0, A1) float OUT; { \
    const float t0__ = __shfl_xor(A0, m); \
    const float t1__ = __shfl_xor(A1, m); \
    OUT = (tid & (m)) ? ((A1) + t1__) : ((A0) + t0__); }

#define RWH(w, VA, VB) { const uu w__ = (w); \
    acc__ += __uint_as_float(w__ << 16) * (VA); \
    acc__ += __uint_as_float(w__ & 0xFFFF0000u) * (VB); }

#define ROWBODY(P) \
    RWH(P[0],  vz0.x, vz0.y) RWH(P[1],  vz0.z, vz0.w) \
    RWH(P[2],  vz1.x, vz1.y) RWH(P[3],  vz1.z, vz1.w) \
    RWH(P[4],  vz2.x, vz2.y) RWH(P[5],  vz2.z, vz2.w) \
    RWH(P[6],  vz3.x, vz3.y) RWH(P[7],  vz3.z, vz3.w) \
    RWH(P[8],  vz4.x, vz4.y) RWH(P[9],  vz4.z, vz4.w) \
    RWH(P[10], vz5.x, vz5.y) RWH(P[11], vz5.z, vz5.w) \
    RWH(P[12], vz6.x, vz6.y) RWH(P[13], vz6.z, vz6.w) \
    RWH(P[14], vz7.x, vz7.y) RWH(P[15], vz7.z, vz7.w)

#define ROWK(k) { float acc__ = 0.0f; \
    if (32*(k) < nr && cact) { ROWBODY(R##k) } \
    acc__ += __shfl_xor(acc__, 32); \
    if ((tid & 32) == 0) red[wv][tr + 32*(k)] = acc__; }

#define ROWLDSQ(k,q, VA0,VB0,VA1,VB1,VA2,VB2,VA3,VB3) { \
    uint4 t__ = *SPQ(k,q); \
    RWH(t__.x, VA0, VB0) RWH(t__.y, VA1, VB1) \
    RWH(t__.z, VA2, VB2) RWH(t__.w, VA3, VB3) }

#define ROWLDSK(k) { float acc__ = 0.0f; \
    if (32*(k) < nr && cact) { \
      ROWLDSQ(k,0, vz0.x,vz0.y, vz0.z,vz0.w, vz1.x,vz1.y, vz1.z,vz1.w) \
      ROWLDSQ(k,1, vz2.x,vz2.y, vz2.z,vz2.w, vz3.x,vz3.y, vz3.z,vz3.w) \
      ROWLDSQ(k,2, vz4.x,vz4.y, vz4.z,vz4.w, vz5.x,vz5.y, vz5.z,vz5.w) \
      ROWLDSQ(k,3, vz6.x,vz6.y, vz6.z,vz6.w, vz7.x,vz7.y, vz7.z,vz7.w) } \
    acc__ += __shfl_xor(acc__, 32); \
    if ((tid & 32) == 0) red[wv][tr + 32*(k)] = acc__; }

#pragma unroll 1
    for (int it = 0; it < 10; ++it) {
        // ---- col pass: c_j = sum_i a_ij u_i (cols of one tc live in one half-wave)
        float ca0=0.0f,ca1=0.0f,ca2=0.0f,ca3=0.0f,ca4=0.0f,ca5=0.0f,ca6=0.0f,ca7=0.0f,
              ca8=0.0f,ca9=0.0f,ca10=0.0f,ca11=0.0f,ca12=0.0f,ca13=0.0f,ca14=0.0f,ca15=0.0f,
              ca16=0.0f,ca17=0.0f,ca18=0.0f,ca19=0.0f,ca20=0.0f,ca21=0.0f,ca22=0.0f,ca23=0.0f,
              ca24=0.0f,ca25=0.0f,ca26=0.0f,ca27=0.0f,ca28=0.0f,ca29=0.0f,ca30=0.0f,ca31=0.0f;
        RPTK12(COLK)
        COLLDS(12) COLLDS(13) COLLDS(14) COLLDS(15)
        // 32-lane tree; all lanes participate (accs are 0 where masked)
        TST(1, d0,  ca0,  ca1)  TST(1, d1,  ca2,  ca3)  TST(1, d2,  ca4,  ca5)  TST(1, d3,  ca6,  ca7)
        TST(1, d4,  ca8,  ca9)  TST(1, d5,  ca10, ca11) TST(1, d6,  ca12, ca13) TST(1, d7,  ca14, ca15)
        TST(1, d8,  ca16, ca17) TST(1, d9,  ca18, ca19) TST(1, d10, ca20, ca21) TST(1, d11, ca22, ca23)
        TST(1, d12, ca24, ca25) TST(1, d13, ca26, ca27) TST(1, d14, ca28, ca29) TST(1, d15, ca30, ca31)
        TST(2, e0, d0, d1)   TST(2, e1, d2, d3)   TST(2, e2, d4, d5)   TST(2, e3, d6, d7)
        TST(2, e4, d8, d9)   TST(2, e5, d10, d11) TST(2, e6, d12, d13) TST(2, e7, d14, d15)
        TST(4, f0, e0, e1) TST(4, f1, e2, e3) TST(4, f2, e4, e5) TST(4, f3, e6, e7)
        TST(8, g0, f0, f1) TST(8, g1, f2, f3)
        TST(16, h0, g0, g1)
        // final col id == tid; write v_j
        sh_v[tid] = (h0 > 0.0f) ? 1.0f / h0 : 1.0f;
        __syncthreads();

        // ---- row pass: r_i = sum_j a_ij v_j
        float4 vz0 = *(const float4*)&sh_v[c0 +  0];
        float4 vz1 = *(const float4*)&sh_v[c0 +  4];
        float4 vz2 = *(const float4*)&sh_v[c0 +  8];
        float4 vz3 = *(const float4*)&sh_v[c0 + 12];
        float4 vz4 = *(const float4*)&sh_v[c0 + 16];
        float4 vz5 = *(const float4*)&sh_v[c0 + 20];
        float4 vz6 = *(const float4*)&sh_v[c0 + 24];
        float4 vz7 = *(const float4*)&sh_v[c0 + 28];
        RPTK12(ROWK)
        ROWLDSK(12) ROWLDSK(13) ROWLDSK(14) ROWLDSK(15)
        __syncthreads();
        {   // u_i = 1 / sum of 8 wave-partials; row id == tid
            float ss = red[0][tid] + red[1][tid] + red[2][tid] + red[3][tid]
                     + red[4][tid] + red[5][tid] + red[6][tid] + red[7][tid];
            sh_u[tid] = (ss > 0.0f) ? 1.0f / ss : 1.0f;
        }
        __syncthreads();
    }

    // ---- epilogue: out = a * u_i * v_j, all stores wave-coalesced via LDS staging
    float4 vz0 = *(const float4*)&sh_v[c0 +  0];
    float4 vz1 = *(const float4*)&sh_v[c0 +  4];
    float4 vz2 = *(const float4*)&sh_v[c0 +  8];
    float4 vz3 = *(const float4*)&sh_v[c0 + 12];
    float4 vz4 = *(const float4*)&sh_v[c0 + 16];
    float4 vz5 = *(const float4*)&sh_v[c0 + 20];
    float4 vz6 = *(const float4*)&sh_v[c0 + 24];
    float4 vz7 = *(const float4*)&sh_v[c0 + 28];

#define EPW(w, UK, VA, VB, OX, OY) { const uu w__ = (w); \
    OX = __uint_as_float(w__ << 16) * (UK) * (VA); \
    OY = __uint_as_float(w__ & 0xFFFF0000u) * (UK) * (VB); }

    float* const redf = (float*)red;      // [8][512] f32 staging, quad-swizzled
    float* const stF  = (float*)spill;    // [32][512] f32 staging (chunks 12+13 region)

    // spill rows k=12..15 first (frees the spill region), via red[] in 8-row subchunks
#define STSPILLK(k) \
    if (32*(k) >= nr) { \
        const float4 z__ = make_float4(0.f,0.f,0.f,0.f); \
        _Pragma("unroll") \
        for (int i__ = 0; i__ < 8; ++i__) { \
            const int f__ = i__*512 + tid; \
            ob4[(size_t)(32*(k) + (f__ >> 7))*128 + (f__ & 127)] = z__; \
        } \
    } else { \
        for (int rg__ = 0; rg__ < 4; ++rg__) { \
            if ((tr >> 3) == rg__) { \
                const float uk__ = sh_u[tr + 32*(k)]; \
                float* sr__ = redf + (tr & 7)*512; \
                const int x__ = tr & 7; \
                uint4 q0__ = *SPQ(k,0); uint4 q1__ = *SPQ(k,1); \
                uint4 q2__ = *SPQ(k,2); uint4 q3__ = *SPQ(k,3); \
                float4 o__; \
                EPW(q0__.x, uk__, vz0.x, vz0.y, o__.x, o__.y) EPW(q0__.y, uk__, vz0.z, vz0.w, o__.z, o__.w) \
                *(float4*)&sr__[((((tc<<3)+0) ^ x__) << 2)] = o__; \
                EPW(q0__.z, uk__, vz1.x, vz1.y, o__.x, o__.y) EPW(q0__.w, uk__, vz1.z, vz1.w, o__.z, o__.w) \
                *(float4*)&sr__[((((tc<<3)+1) ^ x__) << 2)] = o__; \
                EPW(q1__.x, uk__, vz2.x, vz2.y, o__.x, o__.y) EPW(q1__.y, uk__, vz2.z, vz2.w, o__.z, o__.w) \
                *(float4*)&sr__[((((tc<<3)+2) ^ x__) << 2)] = o__; \
                EPW(q1__.z, uk__, vz3.x, vz3.y, o__.x, o__.y) EPW(q1__.w, uk__, vz3.z, vz3.w, o__.z, o__.w) \
                *(float4*)&sr__[((((tc<<3)+3) ^ x__) << 2)] = o__; \
                EPW(q2__.x, uk__, vz4.x, vz4.y, o__.x, o__.y) EPW(q2__.y, uk__, vz4.z, vz4.w, o__.z, o__.w) \
                *(float4*)&sr__[((((tc<<3)+4) ^ x__) << 2)] = o__; \
                EPW(q2__.z, uk__, vz5.x, vz5.y, o__.x, o__.y) EPW(q2__.w, uk__, vz5.z, vz5.w, o__.z, o__.w) \
                *(float4*)&sr__[((((tc<<3)+5) ^ x__) << 2)] = o__; \
                EPW(q3__.x, uk__, vz6.x, vz6.y, o__.x, o__.y) EPW(q3__.y, uk__, vz6.z, vz6.w, o__.z, o__.w) \
                *(float4*)&sr__[((((tc<<3)+6) ^ x__) << 2)] = o__; \
                EPW(q3__.z, uk__, vz7.x, vz7.y, o__.x, o__.y) EPW(q3__.w, uk__, vz7.z, vz7.w, o__.z, o__.w) \
                *(float4*)&sr__[((((tc<<3)+7) ^ x__) << 2)] = o__; \
            } \
            __syncthreads(); \
            _Pragma("unroll") \
            for (int i__ = 0; i__ < 2; ++i__) { \
                const int f__ = i__*512 + tid; \
                const int r8__ = f__ >> 7; const int bb__ = f__ & 127; \
                float4 o__ = *(const float4*)&redf[r8__*512 + ((bb__ ^ r8__) << 2)]; \
                ob4[(size_t)(32*(k) + (rg__<<3) + r8__)*128 + bb__] = o__; \
            } \
            __syncthreads(); \
        } }
    STSPILLK(12); STSPILLK(13); STSPILLK(14); STSPILLK(15);

    // register rows k=0..11 via the freed 64KB spill region
#define STREGK(k) { \
    if (32*(k) < nr) { \
        const float uk__ = sh_u[tr + 32*(k)]; \
        float* sr__ = stF + tr*512; \
        const int x__ = tr & 7; \
        float4 o__; \
        EPW(R##k[0],  uk__, vz0.x, vz0.y, o__.x, o__.y) EPW(R##k[1],  uk__, vz0.z, vz0.w, o__.z, o__.w) \
        *(float4*)&sr__[((((tc<<3)+0) ^ x__) << 2)] = o__; \
        EPW(R##k[2],  uk__, vz1.x, vz1.y, o__.x, o__.y) EPW(R##k[3],  uk__, vz1.z, vz1.w, o__.z, o__.w) \
        *(float4*)&sr__[((((tc<<3)+1) ^ x__) << 2)] = o__; \
        EPW(R##k[4],  uk__, vz2.x, vz2.y, o__.x, o__.y) EPW(R##k[5],  uk__, vz2.z, vz2.w, o__.z, o__.w) \
        *(float4*)&sr__[((((tc<<3)+2) ^ x__) << 2)] = o__; \
        EPW(R##k[6],  uk__, vz3.x, vz3.y, o__.x, o__.y) EPW(R##k[7],  uk__, vz3.z, vz3.w, o__.z, o__.w) \
        *(float4*)&sr__[((((tc<<3)+3) ^ x__) << 2)] = o__; \
        EPW(R##k[8],  uk__, vz4.x, vz4.y, o__.x, o__.y) EPW(R##k[9],  uk__, vz4.z, vz4.w, o__.z, o__.w) \
        *(float4*)&sr__[((((tc<<3)+4) ^ x__) << 2)] = o__; \
        EPW(R##k[10], uk__, vz5.x, vz5.y, o__.x, o__.y) EPW(R##k[11], uk__, vz5.z, vz5.w, o__.z, o__.w) \
        *(float4*)&sr__[((((tc<<3)+5) ^ x__) << 2)] = o__; \
        EPW(R##k[12], uk__, vz6.x, vz6.y, o__.x, o__.y) EPW(R##k[13], uk__, vz6.z, vz6.w, o__.z, o__.w) \
        *(float4*)&sr__[((((tc<<3)+6) ^ x__) << 2)] = o__; \
        EPW(R##k[14], uk__, vz7.x, vz7.y, o__.x, o__.y) EPW(R##k[15], uk__, vz7.z, vz7.w, o__.z, o__.w) \
        *(float4*)&sr__[((((tc<<3)+7) ^ x__) << 2)] = o__; \
        __syncthreads(); \
        _Pragma("unroll") \
        for (int i__ = 0; i__ < 8; ++i__) { \
            const int f__ = i__*512 + tid; \
            const int rr__ = f__ >> 7; const int bb__ = f__ & 127; \
            float4 o2__ = *(const float4*)&stF[rr__*512 + ((bb__ ^ (rr__ & 7)) << 2)]; \
            ob4[(size_t)(32*(k) + rr__)*128 + bb__] = o2__; \
        } \
        __syncthreads(); \
    } else { \
        const float4 z__ = make_float4(0.f,0.f,0.f,0.f); \
        _Pragma("unroll") \
        for (int i__ = 0; i__ < 8; ++i__) { \
            const int f__ = i__*512 + tid; \
            ob4[(size_t)(32*(k) + (f__ >> 7))*128 + (f__ & 127)] = z__; \
        } \
    } }
    RPTK12(STREGK)
}

extern "C" void kernel_launch(void* const* d_in, const int* in_sizes, int n_in,
                              void* d_out, int out_size, void* d_ws, size_t ws_size,
                              hipStream_t stream) {
    const float* s     = (const float*)d_in[0];
    const int*   nrows = (const int*)d_in[1];
    const int*   ncols = (const int*)d_in[2];
    float*       out   = (float*)d_out;
    const int B = in_sizes[1];   // 256 batches, one 512-thread block (one CU) each
    sinkhorn_kernel<<<dim3(B), dim3(512), 0, stream>>>(s, nrows, ncols, out);
}